// Round 1
// baseline (3438.337 us; speedup 1.0000x reference)
//
#include <hip/hip_runtime.h>

// MomentumLSTM: 2-layer LSTM (B=32768,T=60,D=7,H1=64,H2=32) + dense(16)+sigmoid head.
// Strategy: pure-fp32 VALU kernel. One wave = 64 lanes = 64 L1 hidden units,
// NB=8 batch elements per wave held in registers. Weights live in LDS,
// pre-interleaved so each lane's per-k fragment is contiguous (b128/b64 reads).
// Cross-lane h broadcast via v_readlane (static batch index, dynamic k).

#define NB 8
#define THREADS 512
#define WAVES 8
#define BATCH_PER_BLOCK (NB * WAVES)        // 64
#define NBLOCKS (32768 / BATCH_PER_BLOCK)   // 512

// ---- LDS layout (float offsets) ----
#define W1HH 0            // [k=64][256]  (k, 4*j+g) = Whh1[g*64+j][k]
#define W1IH 16384        // [d=7][256]   (d, 4*j+g) = Wih1[g*64+j][d]
#define B1   18176        // [256]        (4*j+g)    = bih1+bhh1
#define W2IH 18432        // [k=64][128]  (k, 2*j+p) = Wih2[(j&63)+p*64][k]
#define W2HH 26624        // [k=32][128]  (k, 2*j+p) = Whh2[(j&63)+p*64][k]
#define B2   30720        // [128]
#define WD   30848        // [16][32] row-major
#define BD   31360        // [16]
#define WO   31376        // [16]
#define BO   31392        // [1]
#define H2F  31396        // [8 waves][8 b][32 u] scratch for epilogue
#define SMEM_FLOATS (H2F + WAVES * NB * 32)
#define SMEM_BYTES (SMEM_FLOATS * 4)

#define L2E 1.44269504f

__device__ __forceinline__ float rl(float v, int lane) {
    return __builtin_bit_cast(float, __builtin_amdgcn_readlane(__builtin_bit_cast(int, v), lane));
}
__device__ __forceinline__ float fsig(float x) {
    float e = __builtin_amdgcn_exp2f(-L2E * x);
    return __builtin_amdgcn_rcpf(1.0f + e);
}
__device__ __forceinline__ float ftanh(float x) {
    float e = __builtin_amdgcn_exp2f((2.0f * L2E) * x);
    float r = __builtin_amdgcn_rcpf(1.0f + e);
    return __builtin_fmaf(-2.0f, r, 1.0f);
}

__global__ void __launch_bounds__(THREADS, 1) lstm_fused_kernel(
    const float* __restrict__ x,
    const float* __restrict__ Wih1, const float* __restrict__ Whh1,
    const float* __restrict__ bih1, const float* __restrict__ bhh1,
    const float* __restrict__ Wih2, const float* __restrict__ Whh2,
    const float* __restrict__ bih2, const float* __restrict__ bhh2,
    const float* __restrict__ Wd, const float* __restrict__ bd,
    const float* __restrict__ Wo, const float* __restrict__ bo,
    float* __restrict__ out)
{
    extern __shared__ float sm[];
    const int tid = threadIdx.x;

    // ---------------- stage weights into LDS (interleaved layouts) ----------------
    for (int idx = tid; idx < 16384; idx += THREADS) {        // Whh1 [256][64] -> [k][4j+g]
        int k = idx >> 8, col = idx & 255;
        int row = ((col & 3) << 6) | (col >> 2);
        sm[W1HH + idx] = Whh1[row * 64 + k];
    }
    for (int idx = tid; idx < 1792; idx += THREADS) {         // Wih1 [256][7] -> [d][4j+g]
        int d = idx >> 8, col = idx & 255;
        int row = ((col & 3) << 6) | (col >> 2);
        sm[W1IH + idx] = Wih1[row * 7 + d];
    }
    for (int idx = tid; idx < 256; idx += THREADS) {          // combined L1 bias
        int row = ((idx & 3) << 6) | (idx >> 2);
        sm[B1 + idx] = bih1[row] + bhh1[row];
    }
    for (int idx = tid; idx < 8192; idx += THREADS) {         // Wih2 [128][64] -> [k][2j+p]
        int k = idx >> 7, col = idx & 127;
        int row = (col >> 1) + ((col & 1) << 6);
        sm[W2IH + idx] = Wih2[row * 64 + k];
    }
    for (int idx = tid; idx < 4096; idx += THREADS) {         // Whh2 [128][32] -> [k][2j+p]
        int k = idx >> 7, col = idx & 127;
        int row = (col >> 1) + ((col & 1) << 6);
        sm[W2HH + idx] = Whh2[row * 32 + k];
    }
    for (int idx = tid; idx < 128; idx += THREADS) {          // combined L2 bias
        int row = (idx >> 1) + ((idx & 1) << 6);
        sm[B2 + idx] = bih2[row] + bhh2[row];
    }
    if (tid < 512) sm[WD + tid] = Wd[tid];                    // Wd [16][32] linear
    if (tid < 16)  sm[BD + tid] = bd[tid];
    if (tid < 16)  sm[WO + tid] = Wo[tid];
    if (tid == 0)  sm[BO] = bo[0];
    __syncthreads();

    const int wave = tid >> 6;
    const int lane = tid & 63;
    const int bbase = blockIdx.x * BATCH_PER_BLOCK + wave * NB;

    // x loader lanes: lane = 8*b + d holds x[bbase+b][t][d] (d<7; d==7 lane loads dup)
    const int bb = lane >> 3;
    const int dd = (lane & 7) < 7 ? (lane & 7) : 6;
    const float* xp = x + (size_t)(bbase + bb) * (60 * 7) + dd;

    float h1[NB], c1[NB], h2[NB], c2[NB];
#pragma unroll
    for (int b = 0; b < NB; ++b) { h1[b] = 0.f; c1[b] = 0.f; h2[b] = 0.f; c2[b] = 0.f; }

    const float4 bias1 = *(const float4*)&sm[B1 + 4 * lane];
    const float2 bias2 = *(const float2*)&sm[B2 + 2 * lane];

    // layer-2 branchless second activation: lanes<32 -> tanh, lanes>=32 -> sigmoid
    const bool lo = (lane < 32);
    const float a1m = lo ? (2.0f * L2E) : (-L2E);
    const float a1f = lo ? -2.0f : 1.0f;
    const float a1c = lo ? 1.0f : 0.0f;

    float xv = xp[0];

    for (int t = 0; t < 60; ++t) {
        // prefetch next timestep's x (clamped offset keeps it in-bounds at t=59)
        float xn = xp[(t < 59) ? 7 : 0];
        xp += 7;

        // ================= layer 1 (unit = lane) =================
        float p0[NB], p1[NB], p2[NB], p3[NB];
#pragma unroll
        for (int b = 0; b < NB; ++b) { p0[b] = bias1.x; p1[b] = bias1.y; p2[b] = bias1.z; p3[b] = bias1.w; }

#pragma unroll
        for (int d = 0; d < 7; ++d) {                          // input projection (D=7)
            float4 w = *(const float4*)&sm[W1IH + d * 256 + 4 * lane];
#pragma unroll
            for (int b = 0; b < NB; ++b) {
                float s = rl(xv, b * 8 + d);
                p0[b] = __builtin_fmaf(w.x, s, p0[b]);
                p1[b] = __builtin_fmaf(w.y, s, p1[b]);
                p2[b] = __builtin_fmaf(w.z, s, p2[b]);
                p3[b] = __builtin_fmaf(w.w, s, p3[b]);
            }
        }
#pragma unroll 4
        for (int k = 0; k < 64; ++k) {                         // recurrent h1 @ Whh1^T
            float4 w = *(const float4*)&sm[W1HH + k * 256 + 4 * lane];
#pragma unroll
            for (int b = 0; b < NB; ++b) {
                float s = rl(h1[b], k);
                p0[b] = __builtin_fmaf(w.x, s, p0[b]);
                p1[b] = __builtin_fmaf(w.y, s, p1[b]);
                p2[b] = __builtin_fmaf(w.z, s, p2[b]);
                p3[b] = __builtin_fmaf(w.w, s, p3[b]);
            }
        }
#pragma unroll
        for (int b = 0; b < NB; ++b) {                         // gates + state update
            float iv = fsig(p0[b]);
            float fv = fsig(p1[b]);
            float gv = ftanh(p2[b]);
            float ov = fsig(p3[b]);
            c1[b] = __builtin_fmaf(fv, c1[b], iv * gv);
            h1[b] = ov * ftanh(c1[b]);
        }

        // ================= layer 2 (lane j -> gate rows j and j+64) =================
        float q0[NB], q1[NB];
#pragma unroll
        for (int b = 0; b < NB; ++b) { q0[b] = bias2.x; q1[b] = bias2.y; }

#pragma unroll 4
        for (int k = 0; k < 64; ++k) {                         // h1 @ Wih2^T
            float2 w = *(const float2*)&sm[W2IH + k * 128 + 2 * lane];
#pragma unroll
            for (int b = 0; b < NB; ++b) {
                float s = rl(h1[b], k);
                q0[b] = __builtin_fmaf(w.x, s, q0[b]);
                q1[b] = __builtin_fmaf(w.y, s, q1[b]);
            }
        }
#pragma unroll 4
        for (int k = 0; k < 32; ++k) {                         // h2 @ Whh2^T
            float2 w = *(const float2*)&sm[W2HH + k * 128 + 2 * lane];
#pragma unroll
            for (int b = 0; b < NB; ++b) {
                float s = rl(h2[b], k);                        // units live in lanes 0..31
                q0[b] = __builtin_fmaf(w.x, s, q0[b]);
                q1[b] = __builtin_fmaf(w.y, s, q1[b]);
            }
        }
#pragma unroll
        for (int b = 0; b < NB; ++b) {
            float act0 = fsig(q0[b]);                          // i (lanes<32) or f (lanes>=32)
            float e = __builtin_amdgcn_exp2f(a1m * q1[b]);     // tanh g (lo) or sigmoid o (hi)
            float r = __builtin_amdgcn_rcpf(1.0f + e);
            float act1 = __builtin_fmaf(a1f, r, a1c);
            float r0 = __shfl_xor(act0, 32, 64);
            float r1 = __shfl_xor(act1, 32, 64);
            float iv = lo ? act0 : r0;
            float gv = lo ? act1 : r1;
            float fv = lo ? r0 : act0;
            float ov = lo ? r1 : act1;
            c2[b] = __builtin_fmaf(fv, c2[b], iv * gv);
            h2[b] = ov * ftanh(c2[b]);
        }

        xv = xn;
    }

    // ================= epilogue: dense(16)+relu, dense(1)+sigmoid =================
    if (lane < 32) {
#pragma unroll
        for (int b = 0; b < NB; ++b) sm[H2F + wave * 256 + b * 32 + lane] = h2[b];
    }
    __syncthreads();
    {
        const int b = lane >> 3, o0 = lane & 7;                // lane -> (batch, out-unit pair)
        float a0 = sm[BD + o0], a1 = sm[BD + o0 + 8];
        const float* hrow = &sm[H2F + wave * 256 + b * 32];
#pragma unroll 8
        for (int u = 0; u < 32; ++u) {
            float hv = hrow[u];
            a0 = __builtin_fmaf(sm[WD + o0 * 32 + u], hv, a0);
            a1 = __builtin_fmaf(sm[WD + (o0 + 8) * 32 + u], hv, a1);
        }
        a0 = fmaxf(a0, 0.0f);
        a1 = fmaxf(a1, 0.0f);
        float part = sm[WO + o0] * a0 + sm[WO + o0 + 8] * a1;
        part += __shfl_xor(part, 1, 64);
        part += __shfl_xor(part, 2, 64);
        part += __shfl_xor(part, 4, 64);
        float outv = fsig(part + sm[BO]);
        if (o0 == 0) out[bbase + b] = outv;
    }
}

extern "C" void kernel_launch(void* const* d_in, const int* in_sizes, int n_in,
                              void* d_out, int out_size, void* d_ws, size_t ws_size,
                              hipStream_t stream) {
    const float* x    = (const float*)d_in[0];
    const float* Wih1 = (const float*)d_in[1];
    const float* Whh1 = (const float*)d_in[2];
    const float* bih1 = (const float*)d_in[3];
    const float* bhh1 = (const float*)d_in[4];
    const float* Wih2 = (const float*)d_in[5];
    const float* Whh2 = (const float*)d_in[6];
    const float* bih2 = (const float*)d_in[7];
    const float* bhh2 = (const float*)d_in[8];
    const float* Wd   = (const float*)d_in[9];
    const float* bd   = (const float*)d_in[10];
    const float* Wo   = (const float*)d_in[11];
    const float* bo   = (const float*)d_in[12];
    float* out = (float*)d_out;

    (void)hipFuncSetAttribute((const void*)lstm_fused_kernel,
                              hipFuncAttributeMaxDynamicSharedMemorySize, SMEM_BYTES);
    lstm_fused_kernel<<<NBLOCKS, THREADS, SMEM_BYTES, stream>>>(
        x, Wih1, Whh1, bih1, bhh1, Wih2, Whh2, bih2, bhh2, Wd, bd, Wo, bo, out);
}

// Round 2
// 2150.654 us; speedup vs baseline: 1.5987x; 1.5987x over previous
//
#include <hip/hip_runtime.h>

// MomentumLSTM: 2-layer LSTM (B=32768,T=60,D=7,H1=64,H2=32) + dense(16)+sigmoid head.
// R2: 1024-thread blocks (16 waves/CU, 4/SIMD, occupancy 2x) and h1 broadcast via
// wave-private LDS uniform ds_read_b128 instead of v_readlane (moves ~1k VALU
// instrs/t/wave onto the LDS pipe). Weights in LDS, pre-interleaved so each
// lane's per-k fragment is one contiguous float4/float2.

#define NB 8
#define THREADS 1024
#define WAVES 16
#define BATCH_PER_BLOCK (NB * WAVES)        // 128
#define NBLOCKS (32768 / BATCH_PER_BLOCK)   // 256  (exactly 1 block per CU)

// ---- LDS layout (float offsets) ----
#define W1HH 0            // [k=64][256]  (k, 4*j+g) = Whh1[g*64+j][k]
#define W1IH 16384        // [d=7][256]   (d, 4*j+g) = Wih1[g*64+j][d]
#define B1   18176        // [256]        (4*j+g)    = bih1+bhh1
#define W2IH 18432        // [k=64][128]  (k, 2*j+p) = Wih2[(j&63)+p*64][k]
#define W2HH 26624        // [k=32][128]  (k, 2*j+p) = Whh2[(j&63)+p*64][k]
#define B2   30720        // [128]
#define WD   30848        // [16][32] row-major
#define BD   31360        // [16]
#define WO   31376        // [16]
#define BO   31392        // [1]
#define HB1  31396        // [16 waves][64 units][8 b] h1 broadcast (epilogue aliases this)
#define SMEM_FLOATS (HB1 + WAVES * 64 * NB) // 39588 floats = 158352 B  (< 160 KiB)
#define SMEM_BYTES (SMEM_FLOATS * 4)

#define L2E 1.44269504f

__device__ __forceinline__ float rl(float v, int lane) {
    return __builtin_bit_cast(float, __builtin_amdgcn_readlane(__builtin_bit_cast(int, v), lane));
}
__device__ __forceinline__ float fsig(float x) {
    float e = __builtin_amdgcn_exp2f(-L2E * x);
    return __builtin_amdgcn_rcpf(1.0f + e);
}
__device__ __forceinline__ float ftanh(float x) {
    float e = __builtin_amdgcn_exp2f((2.0f * L2E) * x);
    float r = __builtin_amdgcn_rcpf(1.0f + e);
    return __builtin_fmaf(-2.0f, r, 1.0f);
}

__global__ void __launch_bounds__(THREADS, 4) lstm_fused_kernel(
    const float* __restrict__ x,
    const float* __restrict__ Wih1, const float* __restrict__ Whh1,
    const float* __restrict__ bih1, const float* __restrict__ bhh1,
    const float* __restrict__ Wih2, const float* __restrict__ Whh2,
    const float* __restrict__ bih2, const float* __restrict__ bhh2,
    const float* __restrict__ Wd, const float* __restrict__ bd,
    const float* __restrict__ Wo, const float* __restrict__ bo,
    float* __restrict__ out)
{
    extern __shared__ float sm[];
    const int tid = threadIdx.x;

    // ---------------- stage weights into LDS (interleaved layouts) ----------------
    for (int idx = tid; idx < 16384; idx += THREADS) {        // Whh1 [256][64] -> [k][4j+g]
        int k = idx >> 8, col = idx & 255;
        int row = ((col & 3) << 6) | (col >> 2);
        sm[W1HH + idx] = Whh1[row * 64 + k];
    }
    for (int idx = tid; idx < 1792; idx += THREADS) {         // Wih1 [256][7] -> [d][4j+g]
        int d = idx >> 8, col = idx & 255;
        int row = ((col & 3) << 6) | (col >> 2);
        sm[W1IH + idx] = Wih1[row * 7 + d];
    }
    for (int idx = tid; idx < 256; idx += THREADS) {          // combined L1 bias
        int row = ((idx & 3) << 6) | (idx >> 2);
        sm[B1 + idx] = bih1[row] + bhh1[row];
    }
    for (int idx = tid; idx < 8192; idx += THREADS) {         // Wih2 [128][64] -> [k][2j+p]
        int k = idx >> 7, col = idx & 127;
        int row = (col >> 1) + ((col & 1) << 6);
        sm[W2IH + idx] = Wih2[row * 64 + k];
    }
    for (int idx = tid; idx < 4096; idx += THREADS) {         // Whh2 [128][32] -> [k][2j+p]
        int k = idx >> 7, col = idx & 127;
        int row = (col >> 1) + ((col & 1) << 6);
        sm[W2HH + idx] = Whh2[row * 32 + k];
    }
    for (int idx = tid; idx < 128; idx += THREADS) {          // combined L2 bias
        int row = (idx >> 1) + ((idx & 1) << 6);
        sm[B2 + idx] = bih2[row] + bhh2[row];
    }
    if (tid < 512) sm[WD + tid] = Wd[tid];                    // Wd [16][32] linear
    if (tid < 16)  sm[BD + tid] = bd[tid];
    if (tid < 16)  sm[WO + tid] = Wo[tid];
    if (tid == 0)  sm[BO] = bo[0];
    __syncthreads();

    const int wave = tid >> 6;
    const int lane = tid & 63;
    const int bbase = blockIdx.x * BATCH_PER_BLOCK + wave * NB;

    // wave-private h1 broadcast slice: [unit k][b0..7], 512 floats
    float* hb = &sm[HB1 + wave * 512];

    // x loader lanes: lane = 8*b + d holds x[bbase+b][t][d] (d<7; d==7 lane loads dup)
    const int bb = lane >> 3;
    const int dd = (lane & 7) < 7 ? (lane & 7) : 6;
    const float* xp = x + (size_t)(bbase + bb) * (60 * 7) + dd;

    float h2[NB], c1[NB], c2[NB];
#pragma unroll
    for (int b = 0; b < NB; ++b) { c1[b] = 0.f; h2[b] = 0.f; c2[b] = 0.f; }

    // zero-init this wave's h1 broadcast slice (h1(t=-1) = 0)
    {
        float4 z = {0.f, 0.f, 0.f, 0.f};
        *(float4*)&hb[lane * 8 + 0] = z;
        *(float4*)&hb[lane * 8 + 4] = z;
    }

    const float4 bias1 = *(const float4*)&sm[B1 + 4 * lane];
    const float2 bias2 = *(const float2*)&sm[B2 + 2 * lane];

    // layer-2 branchless second activation: lanes<32 -> tanh, lanes>=32 -> sigmoid
    const bool lo = (lane < 32);
    const float a1m = lo ? (2.0f * L2E) : (-L2E);
    const float a1f = lo ? -2.0f : 1.0f;
    const float a1c = lo ? 1.0f : 0.0f;

    float xv = xp[0];

    for (int t = 0; t < 60; ++t) {
        // prefetch next timestep's x (clamped offset keeps it in-bounds at t=59)
        float xn = xp[(t < 59) ? 7 : 0];
        xp += 7;

        // ================= layer 1 (unit = lane) =================
        float p0[NB], p1[NB], p2[NB], p3[NB];
#pragma unroll
        for (int b = 0; b < NB; ++b) { p0[b] = bias1.x; p1[b] = bias1.y; p2[b] = bias1.z; p3[b] = bias1.w; }

#pragma unroll
        for (int d = 0; d < 7; ++d) {                          // input projection (D=7)
            float4 w = *(const float4*)&sm[W1IH + d * 256 + 4 * lane];
#pragma unroll
            for (int b = 0; b < NB; ++b) {
                float s = rl(xv, b * 8 + d);
                p0[b] = __builtin_fmaf(w.x, s, p0[b]);
                p1[b] = __builtin_fmaf(w.y, s, p1[b]);
                p2[b] = __builtin_fmaf(w.z, s, p2[b]);
                p3[b] = __builtin_fmaf(w.w, s, p3[b]);
            }
        }
#pragma unroll 4
        for (int k = 0; k < 64; ++k) {                         // recurrent h1 @ Whh1^T
            float4 w = *(const float4*)&sm[W1HH + k * 256 + 4 * lane];
            float4 s03 = *(const float4*)&hb[k * 8 + 0];       // uniform addr -> broadcast
            float4 s47 = *(const float4*)&hb[k * 8 + 4];
#pragma unroll
            for (int b = 0; b < 4; ++b) {
                float s = (b == 0) ? s03.x : (b == 1) ? s03.y : (b == 2) ? s03.z : s03.w;
                p0[b] = __builtin_fmaf(w.x, s, p0[b]);
                p1[b] = __builtin_fmaf(w.y, s, p1[b]);
                p2[b] = __builtin_fmaf(w.z, s, p2[b]);
                p3[b] = __builtin_fmaf(w.w, s, p3[b]);
            }
#pragma unroll
            for (int b = 4; b < 8; ++b) {
                float s = (b == 4) ? s47.x : (b == 5) ? s47.y : (b == 6) ? s47.z : s47.w;
                p0[b] = __builtin_fmaf(w.x, s, p0[b]);
                p1[b] = __builtin_fmaf(w.y, s, p1[b]);
                p2[b] = __builtin_fmaf(w.z, s, p2[b]);
                p3[b] = __builtin_fmaf(w.w, s, p3[b]);
            }
        }

        float h1n[NB];
#pragma unroll
        for (int b = 0; b < NB; ++b) {                         // gates + state update
            float iv = fsig(p0[b]);
            float fv = fsig(p1[b]);
            float gv = ftanh(p2[b]);
            float ov = fsig(p3[b]);
            c1[b] = __builtin_fmaf(fv, c1[b], iv * gv);
            h1n[b] = ov * ftanh(c1[b]);
        }
        // publish new h1 to this wave's broadcast slice (all prior reads of old
        // values are complete in program order within the wave)
        {
            float4 ha = {h1n[0], h1n[1], h1n[2], h1n[3]};
            float4 hc = {h1n[4], h1n[5], h1n[6], h1n[7]};
            *(float4*)&hb[lane * 8 + 0] = ha;
            *(float4*)&hb[lane * 8 + 4] = hc;
        }

        // ================= layer 2 (lane j -> gate rows j and j+64) =================
        float q0[NB], q1[NB];
#pragma unroll
        for (int b = 0; b < NB; ++b) { q0[b] = bias2.x; q1[b] = bias2.y; }

#pragma unroll 4
        for (int k = 0; k < 64; ++k) {                         // h1 @ Wih2^T
            float2 w = *(const float2*)&sm[W2IH + k * 128 + 2 * lane];
            float4 s03 = *(const float4*)&hb[k * 8 + 0];       // uniform broadcast
            float4 s47 = *(const float4*)&hb[k * 8 + 4];
#pragma unroll
            for (int b = 0; b < 4; ++b) {
                float s = (b == 0) ? s03.x : (b == 1) ? s03.y : (b == 2) ? s03.z : s03.w;
                q0[b] = __builtin_fmaf(w.x, s, q0[b]);
                q1[b] = __builtin_fmaf(w.y, s, q1[b]);
            }
#pragma unroll
            for (int b = 4; b < 8; ++b) {
                float s = (b == 4) ? s47.x : (b == 5) ? s47.y : (b == 6) ? s47.z : s47.w;
                q0[b] = __builtin_fmaf(w.x, s, q0[b]);
                q1[b] = __builtin_fmaf(w.y, s, q1[b]);
            }
        }
#pragma unroll 4
        for (int k = 0; k < 32; ++k) {                         // h2 @ Whh2^T (readlane)
            float2 w = *(const float2*)&sm[W2HH + k * 128 + 2 * lane];
#pragma unroll
            for (int b = 0; b < NB; ++b) {
                float s = rl(h2[b], k);                        // units live in lanes 0..31
                q0[b] = __builtin_fmaf(w.x, s, q0[b]);
                q1[b] = __builtin_fmaf(w.y, s, q1[b]);
            }
        }
#pragma unroll
        for (int b = 0; b < NB; ++b) {
            float act0 = fsig(q0[b]);                          // i (lanes<32) or f (lanes>=32)
            float e = __builtin_amdgcn_exp2f(a1m * q1[b]);     // tanh g (lo) or sigmoid o (hi)
            float r = __builtin_amdgcn_rcpf(1.0f + e);
            float act1 = __builtin_fmaf(a1f, r, a1c);
            float r0 = __shfl_xor(act0, 32, 64);
            float r1 = __shfl_xor(act1, 32, 64);
            float iv = lo ? act0 : r0;
            float gv = lo ? act1 : r1;
            float fv = lo ? r0 : act0;
            float ov = lo ? r1 : act1;
            c2[b] = __builtin_fmaf(fv, c2[b], iv * gv);
            h2[b] = ov * ftanh(c2[b]);
        }

        xv = xn;
    }

    // ===== epilogue: dense(16)+relu, dense(1)+sigmoid (reuses hb slice as scratch) =====
    if (lane < 32) {
#pragma unroll
        for (int b = 0; b < NB; ++b) hb[b * 32 + lane] = h2[b];
    }
    {
        const int b = lane >> 3, o0 = lane & 7;                // lane -> (batch, out-unit pair)
        float a0 = sm[BD + o0], a1 = sm[BD + o0 + 8];
        const float* hrow = &hb[b * 32];
#pragma unroll 8
        for (int u = 0; u < 32; ++u) {
            float hv = hrow[u];
            a0 = __builtin_fmaf(sm[WD + o0 * 32 + u], hv, a0);
            a1 = __builtin_fmaf(sm[WD + (o0 + 8) * 32 + u], hv, a1);
        }
        a0 = fmaxf(a0, 0.0f);
        a1 = fmaxf(a1, 0.0f);
        float part = sm[WO + o0] * a0 + sm[WO + o0 + 8] * a1;
        part += __shfl_xor(part, 1, 64);
        part += __shfl_xor(part, 2, 64);
        part += __shfl_xor(part, 4, 64);
        float outv = fsig(part + sm[BO]);
        if (o0 == 0) out[bbase + b] = outv;
    }
}

extern "C" void kernel_launch(void* const* d_in, const int* in_sizes, int n_in,
                              void* d_out, int out_size, void* d_ws, size_t ws_size,
                              hipStream_t stream) {
    const float* x    = (const float*)d_in[0];
    const float* Wih1 = (const float*)d_in[1];
    const float* Whh1 = (const float*)d_in[2];
    const float* bih1 = (const float*)d_in[3];
    const float* bhh1 = (const float*)d_in[4];
    const float* Wih2 = (const float*)d_in[5];
    const float* Whh2 = (const float*)d_in[6];
    const float* bih2 = (const float*)d_in[7];
    const float* bhh2 = (const float*)d_in[8];
    const float* Wd   = (const float*)d_in[9];
    const float* bd   = (const float*)d_in[10];
    const float* Wo   = (const float*)d_in[11];
    const float* bo   = (const float*)d_in[12];
    float* out = (float*)d_out;

    (void)hipFuncSetAttribute((const void*)lstm_fused_kernel,
                              hipFuncAttributeMaxDynamicSharedMemorySize, SMEM_BYTES);
    lstm_fused_kernel<<<NBLOCKS, THREADS, SMEM_BYTES, stream>>>(
        x, Wih1, Whh1, bih1, bhh1, Wih2, Whh2, bih2, bhh2, Wd, bd, Wo, bo, out);
}

// Round 3
// 482.390 us; speedup vs baseline: 7.1277x; 4.4583x over previous
//
#include <hip/hip_runtime.h>

// MomentumLSTM R3: MFMA (32x32x16 bf16) formulation.
// Wave = 32 batch columns (N), gates = M, K = recurrent dim. Weights split
// hi/lo bf16 (error ~2^-17) and staged as pre-built A-fragments in LDS.
// h-state redistribution C-frag -> B-frag via wave-private XOR-swizzled LDS.
// L1 bias fused into x-ktile (k=7 vs B=1.0, lo at k=15). L2 bias = 1 extra ktile.
// Loop pipelines L2(t-1) MFMAs with L1(t) MFMAs (both need only t-1 state).

using f32x16 = __attribute__((ext_vector_type(16))) float;
using s16x8  = __attribute__((ext_vector_type(8)))  short;
typedef unsigned int uint;
typedef unsigned short ushort;

#define THREADS 256
#define NBLOCKS 256

// ---- LDS byte offsets ----
#define WHH1F 0          // [8mt][4kt][2sp] x 1KB frags = 64 KB
#define WIH2F 65536      // [4mt][4kt][2sp] = 32 KB
#define WHH2F 98304      // [4mt][2kt][2sp] = 16 KB
#define WIH1F 114688     // [8mt] x 1KB (k0-6 Whi, k7 b_hi, k8-14 Wlo, k15 b_lo)
#define B2F   122880     // [4mt] x 1KB (k0 = b2_hi, k1 = b2_lo)
#define WDH   126976     // Wd [16][32] f32
#define BDH   129024
#define WOH   129088
#define BOH   129152
#define XCHG  129168     // per-wave: h1buf 4KB + h2buf 2KB + xbuf 512B
#define WSTRIDE 7168
#define SMEM_BYTES (XCHG + 4 * WSTRIDE)   // 157840 < 163840

#define L2E 1.44269504f

__device__ __forceinline__ float fsig(float v) {
    float e = __builtin_amdgcn_exp2f(-L2E * v);
    return __builtin_amdgcn_rcpf(1.0f + e);
}
__device__ __forceinline__ float ftanh(float v) {
    float e = __builtin_amdgcn_exp2f((2.0f * L2E) * v);
    float r = __builtin_amdgcn_rcpf(1.0f + e);
    return __builtin_fmaf(-2.0f, r, 1.0f);
}
__device__ __forceinline__ ushort bfhi(float w) {
    uint u = __builtin_bit_cast(uint, w);
    return (ushort)((u + 0x7fffu + ((u >> 16) & 1u)) >> 16);
}
__device__ __forceinline__ ushort bfpart(float w, int sp) {   // sp0: hi, sp1: lo
    ushort h = bfhi(w);
    if (sp == 0) return h;
    float hf = __builtin_bit_cast(float, (uint)h << 16);
    return bfhi(w - hf);
}
__device__ __forceinline__ uint pkbf(float a, float b) {      // bf16x2 {b,a}
    uint r;
    asm("v_cvt_pk_bf16_f32 %0, %1, %2" : "=v"(r) : "v"(a), "v"(b));
    return r;
}
__device__ __forceinline__ uint4 pack8(const ushort v[8]) {
    return make_uint4(v[0] | ((uint)v[1] << 16), v[2] | ((uint)v[3] << 16),
                      v[4] | ((uint)v[5] << 16), v[6] | ((uint)v[7] << 16));
}
__device__ __forceinline__ s16x8 ldfrag(const char* p, int imm) {
    return __builtin_bit_cast(s16x8, *(const uint4*)(p + imm));
}
#define MFMA32(a, b, c) \
    __builtin_amdgcn_mfma_f32_32x32x16_bf16((a), __builtin_bit_cast(s16x8, (b)), (c), 0, 0, 0)

__global__ void __launch_bounds__(THREADS, 1) lstm_mfma_kernel(
    const float* __restrict__ x,
    const float* __restrict__ Wih1, const float* __restrict__ Whh1,
    const float* __restrict__ bih1, const float* __restrict__ bhh1,
    const float* __restrict__ Wih2, const float* __restrict__ Whh2,
    const float* __restrict__ bih2, const float* __restrict__ bhh2,
    const float* __restrict__ Wd, const float* __restrict__ bd,
    const float* __restrict__ Wo, const float* __restrict__ bo,
    float* __restrict__ out)
{
    extern __shared__ char smc[];
    float* smf = (float*)smc;
    const int tid = threadIdx.x;

    // ---------------- stage hi/lo bf16 A-fragments ----------------
    // A-frag layout (32x32x16): lane l holds A[row=l&31][k=(l>>5)*8+e], e=0..7.
    for (int i = tid; i < 4096; i += THREADS) {          // Whh1 [256][64]
        int ln = i & 63, f = i >> 6;
        int sp = f & 1, kt = (f >> 1) & 3, mt = f >> 3;
        const float* src = Whh1 + (mt * 32 + (ln & 31)) * 64 + kt * 16 + (ln >> 5) * 8;
        ushort v[8];
#pragma unroll
        for (int e = 0; e < 8; ++e) v[e] = bfpart(src[e], sp);
        *(uint4*)(smc + WHH1F + f * 1024 + ln * 16) = pack8(v);
    }
    for (int i = tid; i < 2048; i += THREADS) {          // Wih2 [128][64]
        int ln = i & 63, f = i >> 6;
        int sp = f & 1, kt = (f >> 1) & 3, mt = f >> 3;
        const float* src = Wih2 + (mt * 32 + (ln & 31)) * 64 + kt * 16 + (ln >> 5) * 8;
        ushort v[8];
#pragma unroll
        for (int e = 0; e < 8; ++e) v[e] = bfpart(src[e], sp);
        *(uint4*)(smc + WIH2F + f * 1024 + ln * 16) = pack8(v);
    }
    for (int i = tid; i < 1024; i += THREADS) {          // Whh2 [128][32]
        int ln = i & 63, f = i >> 6;
        int sp = f & 1, kt = (f >> 1) & 1, mt = f >> 2;
        const float* src = Whh2 + (mt * 32 + (ln & 31)) * 32 + kt * 16 + (ln >> 5) * 8;
        ushort v[8];
#pragma unroll
        for (int e = 0; e < 8; ++e) v[e] = bfpart(src[e], sp);
        *(uint4*)(smc + WHH2F + f * 1024 + ln * 16) = pack8(v);
    }
    for (int i = tid; i < 512; i += THREADS) {           // Wih1 [256][7] + bias1
        int ln = i & 63, mt = i >> 6;
        int G = mt * 32 + (ln & 31), sp = ln >> 5;       // upper k-half holds lo copy
        float b1 = bih1[G] + bhh1[G];
        ushort v[8];
#pragma unroll
        for (int e = 0; e < 8; ++e) {
            float w = (e < 7) ? Wih1[G * 7 + e] : b1;
            v[e] = bfpart(w, sp);
        }
        *(uint4*)(smc + WIH1F + mt * 1024 + ln * 16) = pack8(v);
    }
    for (int i = tid; i < 256; i += THREADS) {           // L2 bias tile
        int ln = i & 63, mt = i >> 6;
        int G = mt * 32 + (ln & 31);
        float b2 = bih2[G] + bhh2[G];
        ushort v[8] = {0, 0, 0, 0, 0, 0, 0, 0};
        if ((ln >> 5) == 0) { v[0] = bfpart(b2, 0); v[1] = bfpart(b2, 1); }
        *(uint4*)(smc + B2F + mt * 1024 + ln * 16) = pack8(v);
    }
    for (int i = tid; i < 512; i += THREADS) smf[WDH / 4 + i] = Wd[i];
    if (tid < 16) { smf[BDH / 4 + tid] = bd[tid]; smf[WOH / 4 + tid] = Wo[tid]; }
    if (tid == 0) smf[BOH / 4] = bo[0];
    __syncthreads();

    // ---------------- per-wave setup ----------------
    const int lane = tid & 63, wave = tid >> 6;
    const int hh = lane >> 5, n = lane & 31;
    const int bbase = blockIdx.x * 128 + wave * 32;
    char* xch = smc + XCHG + wave * WSTRIDE;
    uint* h1b = (uint*)xch;            // [32 n][32 u2] dwords, granule-XOR swizzled
    uint* h2b = (uint*)(xch + 4096);   // [32 n][16 u2]
    uint* xb  = (uint*)(xch + 6144);   // [32 n][4] dwords

    const char* pWhh1 = smc + WHH1F + lane * 16;
    const char* pWih2 = smc + WIH2F + lane * 16;
    const char* pWhh2 = smc + WHH2F + lane * 16;
    const char* pWih1 = smc + WIH1F + lane * 16;
    const char* pB2   = smc + B2F   + lane * 16;

    const float* xp = x + (size_t)(bbase + n) * 420;     // lanes<32 load

    f32x16 Z;
#pragma unroll
    for (int i = 0; i < 16; ++i) Z[i] = 0.0f;

    uint4 h1B[4], h2B[2], xB;
#pragma unroll
    for (int k = 0; k < 4; ++k) h1B[k] = make_uint4(0, 0, 0, 0);
    h2B[0] = make_uint4(0, 0, 0, 0);
    h2B[1] = make_uint4(0, 0, 0, 0);
    const uint4 onesB = make_uint4(hh == 0 ? 0x3F803F80u : 0u, 0u, 0u, 0u);

    float c1s[2][4][4] = {};
    float c2s[4][4] = {};
    float h2n[4][4];
    f32x16 C2l[4];

    float xr[7];
    if (lane < 32) {
#pragma unroll
        for (int d = 0; d < 7; ++d) xr[d] = xp[d];
        uint4 xd;
        xd.x = pkbf(xr[0], xr[1]); xd.y = pkbf(xr[2], xr[3]);
        xd.z = pkbf(xr[4], xr[5]); xd.w = pkbf(xr[6], 1.0f);  // k=7 -> bias slot
        *(uint4*)&xb[lane * 4] = xd;
    }
    xB = *(const uint4*)&xb[n * 4];

    // L2 MFMA block for step (t-1): uses h1B (=h1(t-1)) and h2B (=h2(t-2))
    auto mfma2 = [&]() {
#pragma unroll
        for (int mt = 0; mt < 4; ++mt) {
            f32x16 c = MFMA32(ldfrag(pWih2, (mt * 8 + 0) * 1024), h1B[0], Z);
            c = MFMA32(ldfrag(pWih2, (mt * 8 + 1) * 1024), h1B[0], c);
#pragma unroll
            for (int kt = 1; kt < 4; ++kt) {
                c = MFMA32(ldfrag(pWih2, (mt * 8 + kt * 2 + 0) * 1024), h1B[kt], c);
                c = MFMA32(ldfrag(pWih2, (mt * 8 + kt * 2 + 1) * 1024), h1B[kt], c);
            }
#pragma unroll
            for (int kt = 0; kt < 2; ++kt) {
                c = MFMA32(ldfrag(pWhh2, (mt * 4 + kt * 2 + 0) * 1024), h2B[kt], c);
                c = MFMA32(ldfrag(pWhh2, (mt * 4 + kt * 2 + 1) * 1024), h2B[kt], c);
            }
            c = MFMA32(ldfrag(pB2, mt * 1024), onesB, c);    // + bias2 (hi+lo)
            C2l[mt] = c;
        }
    };
    // L2 activations for step (t-1); publishes h2B
    auto act2 = [&]() {
#pragma unroll
        for (int A = 0; A < 4; ++A)
#pragma unroll
        for (int Bq = 0; Bq < 4; ++Bq) {
            int r = A * 4 + Bq;
            float iv = fsig(C2l[0][r]);
            float fv = fsig(C2l[1][r]);
            float gv = ftanh(C2l[2][r]);
            float ov = fsig(C2l[3][r]);
            float c = __builtin_fmaf(fv, c2s[A][Bq], iv * gv);
            c2s[A][Bq] = c;
            h2n[A][Bq] = ov * ftanh(c);
        }
#pragma unroll
        for (int A = 0; A < 4; ++A) {
            uint d0 = pkbf(h2n[A][0], h2n[A][1]);
            uint d1 = pkbf(h2n[A][2], h2n[A][3]);
            *(uint2*)&h2b[n * 16 + ((A ^ (n & 3)) * 4) + hh * 2] = make_uint2(d0, d1);
        }
#pragma unroll
        for (int kt = 0; kt < 2; ++kt)
            h2B[kt] = *(const uint4*)&h2b[n * 16 + (((kt * 2 + hh) ^ (n & 3)) * 4)];
    };

    // ---------------- time loop ----------------
    for (int t = 0; t < 60; ++t) {
        if (t < 59 && lane < 32) {                       // prefetch x(t+1)
#pragma unroll
            for (int d = 0; d < 7; ++d) xr[d] = xp[(t + 1) * 7 + d];
        }
        // L1 MFMAs (step t): gates1 = Whh1*h1(t-1) + Wih1*x(t) + b1
        f32x16 C1[8];
#pragma unroll
        for (int mt = 0; mt < 8; ++mt) {
            f32x16 c = MFMA32(ldfrag(pWhh1, (mt * 8 + 0) * 1024), h1B[0], Z);
            c = MFMA32(ldfrag(pWhh1, (mt * 8 + 1) * 1024), h1B[0], c);
#pragma unroll
            for (int kt = 1; kt < 4; ++kt) {
                c = MFMA32(ldfrag(pWhh1, (mt * 8 + kt * 2 + 0) * 1024), h1B[kt], c);
                c = MFMA32(ldfrag(pWhh1, (mt * 8 + kt * 2 + 1) * 1024), h1B[kt], c);
            }
            c = MFMA32(ldfrag(pWih1, mt * 1024), xB, c); // x + bias, hi & lo folded
            C1[mt] = c;
        }
        // L2 MFMAs for step t-1 overlap L1's act dependency stall
        if (t > 0) mfma2();
        // L1 activations (step t); lane owns units j = 32*m5 + 8A + 4*hh + Bq, col n
        float h1n[2][4][4];
#pragma unroll
        for (int m5 = 0; m5 < 2; ++m5)
#pragma unroll
        for (int A = 0; A < 4; ++A)
#pragma unroll
        for (int Bq = 0; Bq < 4; ++Bq) {
            int r = A * 4 + Bq;
            float iv = fsig(C1[m5][r]);
            float fv = fsig(C1[2 + m5][r]);
            float gv = ftanh(C1[4 + m5][r]);
            float ov = fsig(C1[6 + m5][r]);
            float c = __builtin_fmaf(fv, c1s[m5][A][Bq], iv * gv);
            c1s[m5][A][Bq] = c;
            h1n[m5][A][Bq] = ov * ftanh(c);
        }
        // h1(t) -> bf16 pairs -> LDS (XOR-swizzled) -> B-fragments
#pragma unroll
        for (int m5 = 0; m5 < 2; ++m5)
#pragma unroll
        for (int A = 0; A < 4; ++A) {
            uint d0 = pkbf(h1n[m5][A][0], h1n[m5][A][1]);
            uint d1 = pkbf(h1n[m5][A][2], h1n[m5][A][3]);
            *(uint2*)&h1b[n * 32 + (((m5 * 4 + A) ^ (n & 7)) * 4) + hh * 2] =
                make_uint2(d0, d1);
        }
#pragma unroll
        for (int kt = 0; kt < 4; ++kt)
            h1B[kt] = *(const uint4*)&h1b[n * 32 + (((kt * 2 + hh) ^ (n & 7)) * 4)];
        // L2 activations (step t-1)
        if (t > 0) act2();
        // pack x(t+1)
        if (t < 59) {
            if (lane < 32) {
                uint4 xd;
                xd.x = pkbf(xr[0], xr[1]); xd.y = pkbf(xr[2], xr[3]);
                xd.z = pkbf(xr[4], xr[5]); xd.w = pkbf(xr[6], 1.0f);
                *(uint4*)&xb[lane * 4] = xd;
            }
            xB = *(const uint4*)&xb[n * 4];
        }
    }
    // final L2 step (t = 59)
    mfma2();
    act2();

    // ---------------- dense head ----------------
#pragma unroll
    for (int A = 0; A < 4; ++A)
#pragma unroll
    for (int Bq = 0; Bq < 4; ++Bq)
        ((float*)h1b)[n * 32 + A * 8 + hh * 4 + Bq] = h2n[A][Bq];   // [col][unit] f32
    if (lane < 32) {
        const float* hcol = (const float*)h1b + lane * 32;
        float acc[16];
#pragma unroll
        for (int o = 0; o < 16; ++o) acc[o] = smf[BDH / 4 + o];
#pragma unroll 4
        for (int u = 0; u < 32; ++u) {
            float hv = hcol[u];
#pragma unroll
            for (int o = 0; o < 16; ++o)
                acc[o] = __builtin_fmaf(smf[WDH / 4 + o * 32 + u], hv, acc[o]);
        }
        float rr = smf[BOH / 4];
#pragma unroll
        for (int o = 0; o < 16; ++o)
            rr = __builtin_fmaf(smf[WOH / 4 + o], fmaxf(acc[o], 0.0f), rr);
        out[bbase + lane] = fsig(rr);
    }
}

extern "C" void kernel_launch(void* const* d_in, const int* in_sizes, int n_in,
                              void* d_out, int out_size, void* d_ws, size_t ws_size,
                              hipStream_t stream) {
    const float* x    = (const float*)d_in[0];
    const float* Wih1 = (const float*)d_in[1];
    const float* Whh1 = (const float*)d_in[2];
    const float* bih1 = (const float*)d_in[3];
    const float* bhh1 = (const float*)d_in[4];
    const float* Wih2 = (const float*)d_in[5];
    const float* Whh2 = (const float*)d_in[6];
    const float* bih2 = (const float*)d_in[7];
    const float* bhh2 = (const float*)d_in[8];
    const float* Wd   = (const float*)d_in[9];
    const float* bd   = (const float*)d_in[10];
    const float* Wo   = (const float*)d_in[11];
    const float* bo   = (const float*)d_in[12];
    float* out = (float*)d_out;

    (void)hipFuncSetAttribute((const void*)lstm_mfma_kernel,
                              hipFuncAttributeMaxDynamicSharedMemorySize, SMEM_BYTES);
    lstm_mfma_kernel<<<NBLOCKS, THREADS, SMEM_BYTES, stream>>>(
        x, Wih1, Whh1, bih1, bhh1, Wih2, Whh2, bih2, bhh2, Wd, bd, Wo, bo, out);
}

// Round 4
// 443.689 us; speedup vs baseline: 7.7494x; 1.0872x over previous
//
#include <hip/hip_runtime.h>

// MomentumLSTM R4: producer/consumer wave specialization.
// 8 waves/block: waves 0-3 (A) = layer-1 LSTM for batch tile (wave&3);
// waves 4-7 (B) = layer-2 LSTM (1-step lag) + x prefetch + dense head.
// One __syncthreads per timestep; h1/x handoff via parity-double-buffered LDS.
// C-frag -> B-frag conversion fully in registers via v_permlane32_swap.
// Weights hi/lo-split bf16 as pre-built A-fragments in LDS (as R3).
// L2 bias rides in the f32 accumulator init (exact, no MFMA).

using f32x16 = __attribute__((ext_vector_type(16))) float;
using s16x8  = __attribute__((ext_vector_type(8)))  short;
using uint2v = __attribute__((ext_vector_type(2)))  unsigned int;
typedef unsigned int uint;
typedef unsigned short ushort;

#define THREADS 512
#define NBLOCKS 256

// ---- LDS byte offsets ----
#define WHH1F 0          // [8mt][4kt][2sp] x 1KB A-frags = 64 KB
#define WIH2F 65536      // [4mt][4kt][2sp] = 32 KB
#define WHH2F 98304      // [4mt][2kt][2sp] = 16 KB
#define WIH1F 114688     // [8mt] x 1KB (k0-6 W_hi, k7 b_hi, k8-14 W_lo, k15 b_lo)
#define WDH   122880     // Wd [16][32] f32 (2048 B)
#define BDH   124928
#define WOH   124992
#define BOH   125056
#define XCHG  125184     // per tile: h1frag 2x4KB + xbuf 2x512B = 9216 B
#define TSTR  9216
#define SMEM_BYTES (XCHG + 4 * TSTR)   // 162048 < 163840

#define L2E 1.44269504f

__device__ __forceinline__ float fsig(float v) {
    float e = __builtin_amdgcn_exp2f(-L2E * v);
    return __builtin_amdgcn_rcpf(1.0f + e);
}
__device__ __forceinline__ float ftanh(float v) {
    float e = __builtin_amdgcn_exp2f((2.0f * L2E) * v);
    float r = __builtin_amdgcn_rcpf(1.0f + e);
    return __builtin_fmaf(-2.0f, r, 1.0f);
}
__device__ __forceinline__ ushort bfhi(float w) {
    uint u = __builtin_bit_cast(uint, w);
    return (ushort)((u + 0x7fffu + ((u >> 16) & 1u)) >> 16);
}
__device__ __forceinline__ ushort bfpart(float w, int sp) {   // sp0: hi, sp1: lo
    ushort h = bfhi(w);
    if (sp == 0) return h;
    float hf = __builtin_bit_cast(float, (uint)h << 16);
    return bfhi(w - hf);
}
__device__ __forceinline__ uint pkbf(float a, float b) {      // bf16x2 {lo=a, hi=b}
    uint r;
    asm("v_cvt_pk_bf16_f32 %0, %1, %2" : "=v"(r) : "v"(a), "v"(b));
    return r;
}
__device__ __forceinline__ uint4 pack8(const ushort v[8]) {
    return make_uint4(v[0] | ((uint)v[1] << 16), v[2] | ((uint)v[3] << 16),
                      v[4] | ((uint)v[5] << 16), v[6] | ((uint)v[7] << 16));
}
__device__ __forceinline__ s16x8 ldfrag(const char* p, int imm) {
    return __builtin_bit_cast(s16x8, *(const uint4*)(p + imm));
}
#define MFMA32(a, b, c) \
    __builtin_amdgcn_mfma_f32_32x32x16_bf16((a), __builtin_bit_cast(s16x8, (b)), (c), 0, 0, 0)
#define PLSWAP(a, b) __builtin_amdgcn_permlane32_swap((a), (b), false, false)

__global__ void __launch_bounds__(THREADS, 2) lstm_mfma_kernel(
    const float* __restrict__ x,
    const float* __restrict__ Wih1, const float* __restrict__ Whh1,
    const float* __restrict__ bih1, const float* __restrict__ bhh1,
    const float* __restrict__ Wih2, const float* __restrict__ Whh2,
    const float* __restrict__ bih2, const float* __restrict__ bhh2,
    const float* __restrict__ Wd, const float* __restrict__ bd,
    const float* __restrict__ Wo, const float* __restrict__ bo,
    float* __restrict__ out)
{
    extern __shared__ char smc[];
    float* smf = (float*)smc;
    const int tid = threadIdx.x;

    // ---------------- stage hi/lo bf16 A-fragments ----------------
    // A-frag (32x32x16): lane l holds A[row=l&31][k=(l>>5)*8+e], e=0..7.
    for (int i = tid; i < 4096; i += THREADS) {          // Whh1 [256][64]
        int ln = i & 63, f = i >> 6;
        int sp = f & 1, kt = (f >> 1) & 3, mt = f >> 3;
        const float* src = Whh1 + (mt * 32 + (ln & 31)) * 64 + kt * 16 + (ln >> 5) * 8;
        ushort v[8];
#pragma unroll
        for (int e = 0; e < 8; ++e) v[e] = bfpart(src[e], sp);
        *(uint4*)(smc + WHH1F + f * 1024 + ln * 16) = pack8(v);
    }
    for (int i = tid; i < 2048; i += THREADS) {          // Wih2 [128][64]
        int ln = i & 63, f = i >> 6;
        int sp = f & 1, kt = (f >> 1) & 3, mt = f >> 3;
        const float* src = Wih2 + (mt * 32 + (ln & 31)) * 64 + kt * 16 + (ln >> 5) * 8;
        ushort v[8];
#pragma unroll
        for (int e = 0; e < 8; ++e) v[e] = bfpart(src[e], sp);
        *(uint4*)(smc + WIH2F + f * 1024 + ln * 16) = pack8(v);
    }
    for (int i = tid; i < 1024; i += THREADS) {          // Whh2 [128][32]
        int ln = i & 63, f = i >> 6;
        int sp = f & 1, kt = (f >> 1) & 1, mt = f >> 2;
        const float* src = Whh2 + (mt * 32 + (ln & 31)) * 32 + kt * 16 + (ln >> 5) * 8;
        ushort v[8];
#pragma unroll
        for (int e = 0; e < 8; ++e) v[e] = bfpart(src[e], sp);
        *(uint4*)(smc + WHH2F + f * 1024 + ln * 16) = pack8(v);
    }
    for (int i = tid; i < 512; i += THREADS) {           // Wih1 [256][7] + bias1
        int ln = i & 63, mt = i >> 6;
        int G = mt * 32 + (ln & 31), sp = ln >> 5;       // upper k-half = lo split
        float b1 = bih1[G] + bhh1[G];
        ushort v[8];
#pragma unroll
        for (int e = 0; e < 8; ++e) {
            float w = (e < 7) ? Wih1[G * 7 + e] : b1;
            v[e] = bfpart(w, sp);
        }
        *(uint4*)(smc + WIH1F + mt * 1024 + ln * 16) = pack8(v);
    }
    for (int i = tid; i < 512; i += THREADS) smf[WDH / 4 + i] = Wd[i];
    if (tid < 16) { smf[BDH / 4 + tid] = bd[tid]; smf[WOH / 4 + tid] = Wo[tid]; }
    if (tid == 0) smf[BOH / 4] = bo[0];

    // ---------------- per-wave setup ----------------
    const int lane = tid & 63, wave = tid >> 6;
    const bool wA = (wave < 4);
    const int tile = wave & 3;
    const int hh = lane >> 5, n = lane & 31;
    const int bbase = blockIdx.x * 128 + tile * 32;

    char* h1base = smc + XCHG + tile * TSTR + lane * 16;       // + par*4096 + kt*1024
    char* xbw    = smc + XCHG + tile * TSTR + 8192 + lane * 16;  // writer (lane<32)
    char* xbr    = smc + XCHG + tile * TSTR + 8192 + n * 16;     // reader

    const char* pWhh1 = smc + WHH1F + lane * 16;
    const char* pWih2 = smc + WIH2F + lane * 16;
    const char* pWhh2 = smc + WHH2F + lane * 16;
    const char* pWih1 = smc + WIH1F + lane * 16;

    const float* xp = x + (size_t)(bbase + n) * 420;

    // A state
    uint4 h1F[4];
#pragma unroll
    for (int k = 0; k < 4; ++k) h1F[k] = make_uint4(0, 0, 0, 0);
    float c1s[2][4][4] = {};

    // B state
    uint4 h1Bb[4], h2B[2];
    h2B[0] = make_uint4(0, 0, 0, 0);
    h2B[1] = make_uint4(0, 0, 0, 0);
    float c2s[4][4] = {};
    float h2n[4][4];
    f32x16 C2l[4];
    f32x16 bias2C[4];
    float xr[7];

    if (!wA) {
#pragma unroll
        for (int mt = 0; mt < 4; ++mt)
#pragma unroll
        for (int r = 0; r < 16; ++r) {
            int G = mt * 32 + (r & 3) + 8 * (r >> 2) + 4 * hh;
            bias2C[mt][r] = bih2[G] + bhh2[G];
        }
        if (lane < 32) {                                  // pack x(0) -> parity 0
#pragma unroll
            for (int d = 0; d < 7; ++d) xr[d] = xp[d];
            uint4 xd;
            xd.x = pkbf(xr[0], xr[1]); xd.y = pkbf(xr[2], xr[3]);
            xd.z = pkbf(xr[4], xr[5]); xd.w = pkbf(xr[6], 1.0f);  // k=7 bias slot
            *(uint4*)(xbw + 0) = xd;
        }
    }
    __syncthreads();

    // B's L2 MFMA block for step (t-1): h1Bb = h1(t-1), h2B = h2(t-2)
    auto mfma2 = [&]() {
#pragma unroll
        for (int mt = 0; mt < 4; ++mt) {
            f32x16 c = bias2C[mt];
#pragma unroll
            for (int kt = 0; kt < 4; ++kt) {
                c = MFMA32(ldfrag(pWih2, (mt * 8 + kt * 2 + 0) * 1024), h1Bb[kt], c);
                c = MFMA32(ldfrag(pWih2, (mt * 8 + kt * 2 + 1) * 1024), h1Bb[kt], c);
            }
#pragma unroll
            for (int kt = 0; kt < 2; ++kt) {
                c = MFMA32(ldfrag(pWhh2, (mt * 4 + kt * 2 + 0) * 1024), h2B[kt], c);
                c = MFMA32(ldfrag(pWhh2, (mt * 4 + kt * 2 + 1) * 1024), h2B[kt], c);
            }
            C2l[mt] = c;
        }
    };
    // B's L2 activations for step (t-1); rebuilds h2B frags in-register
    auto act2 = [&]() {
#pragma unroll
        for (int A = 0; A < 4; ++A)
#pragma unroll
        for (int Bq = 0; Bq < 4; ++Bq) {
            int r = A * 4 + Bq;
            float iv = fsig(C2l[0][r]);
            float fv = fsig(C2l[1][r]);
            float gv = ftanh(C2l[2][r]);
            float ov = fsig(C2l[3][r]);
            float c = __builtin_fmaf(fv, c2s[A][Bq], iv * gv);
            c2s[A][Bq] = c;
            h2n[A][Bq] = ov * ftanh(c);
        }
        uint Qh0[4], Qh1[4];
#pragma unroll
        for (int A = 0; A < 4; ++A) {
            Qh0[A] = pkbf(h2n[A][0], h2n[A][1]);
            Qh1[A] = pkbf(h2n[A][2], h2n[A][3]);
        }
#pragma unroll
        for (int kt = 0; kt < 2; ++kt) {
            uint2v sA = PLSWAP(Qh0[kt * 2], Qh0[kt * 2 + 1]);
            uint2v sB = PLSWAP(Qh1[kt * 2], Qh1[kt * 2 + 1]);
            h2B[kt] = make_uint4(sA[0], sB[0], sA[1], sB[1]);
        }
    };

    // ---------------- time loop: one barrier per step ----------------
    for (int t = 0; t < 60; ++t) {
        if (wA) {
            // ===== layer 1, step t =====
            uint4 xB = *(const uint4*)(xbr + (t & 1) * 512);
            f32x16 C1[8];
#pragma unroll
            for (int mt = 0; mt < 8; ++mt) {
                f32x16 c = MFMA32(ldfrag(pWhh1, (mt * 8 + 0) * 1024), h1F[0],
                                  (f32x16){0.f});
                c = MFMA32(ldfrag(pWhh1, (mt * 8 + 1) * 1024), h1F[0], c);
#pragma unroll
                for (int kt = 1; kt < 4; ++kt) {
                    c = MFMA32(ldfrag(pWhh1, (mt * 8 + kt * 2 + 0) * 1024), h1F[kt], c);
                    c = MFMA32(ldfrag(pWhh1, (mt * 8 + kt * 2 + 1) * 1024), h1F[kt], c);
                }
                c = MFMA32(ldfrag(pWih1, mt * 1024), xB, c);   // x + bias (hi&lo)
                C1[mt] = c;
            }
            float h1n[2][4][4];
#pragma unroll
            for (int m5 = 0; m5 < 2; ++m5)
#pragma unroll
            for (int A = 0; A < 4; ++A)
#pragma unroll
            for (int Bq = 0; Bq < 4; ++Bq) {
                int r = A * 4 + Bq;
                float iv = fsig(C1[m5][r]);
                float fv = fsig(C1[2 + m5][r]);
                float gv = ftanh(C1[4 + m5][r]);
                float ov = fsig(C1[6 + m5][r]);
                float c = __builtin_fmaf(fv, c1s[m5][A][Bq], iv * gv);
                c1s[m5][A][Bq] = c;
                h1n[m5][A][Bq] = ov * ftanh(c);
            }
            // C-frag -> B-frag in registers, publish to LDS for B waves
            uint Q0[2][4], Q1[2][4];
#pragma unroll
            for (int m5 = 0; m5 < 2; ++m5)
#pragma unroll
            for (int A = 0; A < 4; ++A) {
                Q0[m5][A] = pkbf(h1n[m5][A][0], h1n[m5][A][1]);
                Q1[m5][A] = pkbf(h1n[m5][A][2], h1n[m5][A][3]);
            }
            char* h1wr = h1base + (t & 1) * 4096;
#pragma unroll
            for (int kt = 0; kt < 4; ++kt) {
                int m5 = kt >> 1, A0 = (kt & 1) * 2;
                uint2v sA = PLSWAP(Q0[m5][A0], Q0[m5][A0 + 1]);
                uint2v sB = PLSWAP(Q1[m5][A0], Q1[m5][A0 + 1]);
                h1F[kt] = make_uint4(sA[0], sB[0], sA[1], sB[1]);
                *(uint4*)(h1wr + kt * 1024) = h1F[kt];
            }
        } else {
            // ===== layer 2, step t-1 =====
            if (t > 0) {
                const char* h1rd = h1base + ((t - 1) & 1) * 4096;
#pragma unroll
                for (int kt = 0; kt < 4; ++kt)
                    h1Bb[kt] = *(const uint4*)(h1rd + kt * 1024);
            }
            if (t < 59 && lane < 32) {                    // prefetch x(t+1)
#pragma unroll
                for (int d = 0; d < 7; ++d) xr[d] = xp[(t + 1) * 7 + d];
            }
            if (t > 0) { mfma2(); act2(); }
            if (t < 59 && lane < 32) {                    // pack x(t+1)
                uint4 xd;
                xd.x = pkbf(xr[0], xr[1]); xd.y = pkbf(xr[2], xr[3]);
                xd.z = pkbf(xr[4], xr[5]); xd.w = pkbf(xr[6], 1.0f);
                *(uint4*)(xbw + ((t + 1) & 1) * 512) = xd;
            }
        }
        __syncthreads();
    }

    if (!wA) {
        // final L2 step (t=59): h1(59) is in parity 1
#pragma unroll
        for (int kt = 0; kt < 4; ++kt)
            h1Bb[kt] = *(const uint4*)(h1base + 4096 + kt * 1024);
        mfma2();
        act2();

        // ---------------- dense head (parity-0 h1 region as scratch) ----------------
        float* hs = (float*)(smc + XCHG + tile * TSTR);
#pragma unroll
        for (int A = 0; A < 4; ++A)
#pragma unroll
        for (int Bq = 0; Bq < 4; ++Bq)
            hs[n * 32 + A * 8 + hh * 4 + Bq] = h2n[A][Bq];      // [col][unit] f32
        if (lane < 32) {
            const float* hcol = hs + lane * 32;
            float acc[16];
#pragma unroll
            for (int o = 0; o < 16; ++o) acc[o] = smf[BDH / 4 + o];
#pragma unroll 4
            for (int u = 0; u < 32; ++u) {
                float hv = hcol[u];
#pragma unroll
                for (int o = 0; o < 16; ++o)
                    acc[o] = __builtin_fmaf(smf[WDH / 4 + o * 32 + u], hv, acc[o]);
            }
            float rr = smf[BOH / 4];
#pragma unroll
            for (int o = 0; o < 16; ++o)
                rr = __builtin_fmaf(smf[WOH / 4 + o], fmaxf(acc[o], 0.0f), rr);
            out[bbase + lane] = fsig(rr);
        }
    }
}

extern "C" void kernel_launch(void* const* d_in, const int* in_sizes, int n_in,
                              void* d_out, int out_size, void* d_ws, size_t ws_size,
                              hipStream_t stream) {
    const float* x    = (const float*)d_in[0];
    const float* Wih1 = (const float*)d_in[1];
    const float* Whh1 = (const float*)d_in[2];
    const float* bih1 = (const float*)d_in[3];
    const float* bhh1 = (const float*)d_in[4];
    const float* Wih2 = (const float*)d_in[5];
    const float* Whh2 = (const float*)d_in[6];
    const float* bih2 = (const float*)d_in[7];
    const float* bhh2 = (const float*)d_in[8];
    const float* Wd   = (const float*)d_in[9];
    const float* bd   = (const float*)d_in[10];
    const float* Wo   = (const float*)d_in[11];
    const float* bo   = (const float*)d_in[12];
    float* out = (float*)d_out;

    (void)hipFuncSetAttribute((const void*)lstm_mfma_kernel,
                              hipFuncAttributeMaxDynamicSharedMemorySize, SMEM_BYTES);
    lstm_mfma_kernel<<<NBLOCKS, THREADS, SMEM_BYTES, stream>>>(
        x, Wih1, Whh1, bih1, bhh1, Wih2, Whh2, bih2, bhh2, Wd, bd, Wo, bo, out);
}